// Round 1
// baseline (2842.682 us; speedup 1.0000x reference)
//
#include <hip/hip_runtime.h>
#include <cstdint>
#include <cstddef>

#define T_STEPS 64
#define BATCH 512
#define IN_F 784
#define HID 2048
#define OUT_F 10

#define DEC_V 0.9f   // 1 - dt*tau_mem_inv
#define DEC_I 0.8f   // 1 - dt*tau_syn_inv
#define DT_V 0.1f
#define V_TH 0.5f

// ---------------------------------------------------------------------------
// GEMM: C[m,n] = sum_k A[m,k] * W[n,k]
// A: [M, 784] row-major (x chunk), W: [2048, 784] row-major (w1), C: [M, 2048]
// M = tc*512 (always multiple of 128), N = 2048, K = 784 (multiple of 16).
// ---------------------------------------------------------------------------
#define BM 128
#define BN 128
#define BK 16

__global__ __launch_bounds__(256, 2)
void gemm_fc1(const float* __restrict__ A, const float* __restrict__ W,
              float* __restrict__ C) {
  __shared__ float As[BK][BM + 4];
  __shared__ float Ws[BK][BN + 4];
  const int tid = threadIdx.x;
  const int bm = blockIdx.y * BM;
  const int bn = blockIdx.x * BN;
  const int tx = tid & 15;   // 0..15 -> 8 cols each
  const int ty = tid >> 4;   // 0..15 -> 8 rows each
  const int lrow = tid >> 1;       // 0..127 loader row
  const int lk = (tid & 1) * 8;    // 0 or 8

  const float* ap = A + (size_t)(bm + lrow) * IN_F + lk;
  const float* wp = W + (size_t)(bn + lrow) * IN_F + lk;

  // prefetch tile 0
  float4 a0 = *(const float4*)(ap);
  float4 a1 = *(const float4*)(ap + 4);
  float4 w0 = *(const float4*)(wp);
  float4 w1 = *(const float4*)(wp + 4);

  float acc[8][8];
#pragma unroll
  for (int i = 0; i < 8; ++i)
#pragma unroll
    for (int j = 0; j < 8; ++j) acc[i][j] = 0.0f;

  for (int k0 = 0; k0 < IN_F; k0 += BK) {
    __syncthreads();
    As[lk + 0][lrow] = a0.x; As[lk + 1][lrow] = a0.y;
    As[lk + 2][lrow] = a0.z; As[lk + 3][lrow] = a0.w;
    As[lk + 4][lrow] = a1.x; As[lk + 5][lrow] = a1.y;
    As[lk + 6][lrow] = a1.z; As[lk + 7][lrow] = a1.w;
    Ws[lk + 0][lrow] = w0.x; Ws[lk + 1][lrow] = w0.y;
    Ws[lk + 2][lrow] = w0.z; Ws[lk + 3][lrow] = w0.w;
    Ws[lk + 4][lrow] = w1.x; Ws[lk + 5][lrow] = w1.y;
    Ws[lk + 6][lrow] = w1.z; Ws[lk + 7][lrow] = w1.w;
    __syncthreads();
    if (k0 + BK < IN_F) {  // register prefetch of next k-tile overlaps compute
      a0 = *(const float4*)(ap + k0 + BK);
      a1 = *(const float4*)(ap + k0 + BK + 4);
      w0 = *(const float4*)(wp + k0 + BK);
      w1 = *(const float4*)(wp + k0 + BK + 4);
    }
#pragma unroll
    for (int k = 0; k < BK; ++k) {
      float af[8], wf[8];
#pragma unroll
      for (int i = 0; i < 8; ++i) af[i] = As[k][ty * 8 + i];
#pragma unroll
      for (int j = 0; j < 8; ++j) wf[j] = Ws[k][tx * 8 + j];
#pragma unroll
      for (int i = 0; i < 8; ++i)
#pragma unroll
        for (int j = 0; j < 8; ++j)
          acc[i][j] = fmaf(af[i], wf[j], acc[i][j]);
    }
  }

#pragma unroll
  for (int i = 0; i < 8; ++i) {
    float* cp = C + (size_t)(bm + ty * 8 + i) * HID + bn + tx * 8;
    *(float4*)(cp)     = make_float4(acc[i][0], acc[i][1], acc[i][2], acc[i][3]);
    *(float4*)(cp + 4) = make_float4(acc[i][4], acc[i][5], acc[i][6], acc[i][7]);
  }
}

// ---------------------------------------------------------------------------
// LIF state update over a chunk of tc timesteps. One thread per (b,h).
// Reads cur[t,b,h], overwrites it in place with spike z[t,b,h] in {0,1}.
// Order (matches reference): v_dec uses OLD i; i_new = 0.8*i_old + cur_t.
// ---------------------------------------------------------------------------
__global__ __launch_bounds__(256)
void lif_scan(float* __restrict__ cur, float* __restrict__ v1,
              float* __restrict__ i1, int tc) {
  const int idx = blockIdx.x * 256 + threadIdx.x;  // b*HID + h
  float v = v1[idx];
  float ci = i1[idx];
  for (int t = 0; t < tc; ++t) {
    const size_t off = (size_t)t * (BATCH * HID) + idx;
    float c = cur[off];
    float vd = DEC_V * v + DT_V * ci;
    float z = (vd > V_TH) ? 1.0f : 0.0f;
    v = (1.0f - z) * vd;
    ci = DEC_I * ci + c;
    cur[off] = z;
  }
  v1[idx] = v;
  i1[idx] = ci;
}

// ---------------------------------------------------------------------------
// out_cur[t,b,o] = sum_h z[t,b,h] * w_out[o,h].
// Block per b; wave per t-row (4 waves/block, strided over tc).
// Lane handles 32 h (h = jj*256 + lane*4, coalesced float4 z reads); loads
// w_out only where z != 0 (~10% spike rate). 64-lane butterfly reduce.
// ---------------------------------------------------------------------------
__global__ __launch_bounds__(256)
void out_proj(const float* __restrict__ z, const float* __restrict__ wo,
              float* __restrict__ outcur, int tc) {
  const int b = blockIdx.x;
  const int wave = threadIdx.x >> 6;
  const int lane = threadIdx.x & 63;
  for (int t = wave; t < tc; t += 4) {
    const float* zr = z + ((size_t)t * BATCH + b) * HID;
    float acc[OUT_F];
#pragma unroll
    for (int o = 0; o < OUT_F; ++o) acc[o] = 0.0f;
#pragma unroll
    for (int jj = 0; jj < 8; ++jj) {
      const int h = jj * 256 + lane * 4;
      const float4 zv = *(const float4*)(zr + h);
      const float zc[4] = {zv.x, zv.y, zv.z, zv.w};
#pragma unroll
      for (int c = 0; c < 4; ++c) {
        if (zc[c] != 0.0f) {
#pragma unroll
          for (int o = 0; o < OUT_F; ++o)
            acc[o] += wo[o * HID + h + c];
        }
      }
    }
#pragma unroll
    for (int o = 0; o < OUT_F; ++o) {
#pragma unroll
      for (int s = 1; s < 64; s <<= 1)
        acc[o] += __shfl_xor(acc[o], s, 64);
    }
    float vsel = acc[0];
#pragma unroll
    for (int o = 1; o < OUT_F; ++o)
      if (lane == o) vsel = acc[o];
    if (lane < OUT_F)
      outcur[((size_t)t * BATCH + b) * OUT_F + lane] = vsel;
  }
}

// ---------------------------------------------------------------------------
// LI readout scan + max over all T. One thread per (b,o).
// voltages[0] == 0 always, so vmax init 0 is exact.
// ---------------------------------------------------------------------------
__global__ __launch_bounds__(256)
void li_scan(const float* __restrict__ outcur, float* __restrict__ out) {
  const int idx = blockIdx.x * 256 + threadIdx.x;  // b*OUT_F + o
  if (idx >= BATCH * OUT_F) return;
  float vo = 0.f, io = 0.f, vmax = 0.f;
  for (int t = 0; t < T_STEPS; ++t) {
    float oc = outcur[(size_t)t * (BATCH * OUT_F) + idx];
    float von = DEC_V * vo + DT_V * io;
    io = DEC_I * io + oc;
    vo = von;
    vmax = fmaxf(vmax, von);
  }
  out[idx] = vmax;
}

__global__ void zero_state(float* __restrict__ p, int n) {
  int i = blockIdx.x * 256 + threadIdx.x;
  if (i < n) p[i] = 0.0f;
}

// ---------------------------------------------------------------------------
extern "C" void kernel_launch(void* const* d_in, const int* in_sizes, int n_in,
                              void* d_out, int out_size, void* d_ws, size_t ws_size,
                              hipStream_t stream) {
  const float* x  = (const float*)d_in[0];  // [T,B,1,28,28] -> [T*B, 784]
  const float* w1 = (const float*)d_in[1];  // [2048, 784]
  const float* wo = (const float*)d_in[2];  // [10, 2048]
  float* out = (float*)d_out;               // [512, 10]

  // ws layout: v1 | i1 | outcur[T,B,10] | cur[Tc,B,HID]
  float* v1 = (float*)d_ws;
  float* i1 = v1 + (size_t)BATCH * HID;
  float* outcur = i1 + (size_t)BATCH * HID;
  float* cur = outcur + (size_t)T_STEPS * BATCH * OUT_F;

  const size_t base_bytes =
      ((size_t)2 * BATCH * HID + (size_t)T_STEPS * BATCH * OUT_F) * sizeof(float);
  const size_t per_step = (size_t)BATCH * HID * sizeof(float);
  int Tc = 1;
  if (ws_size > base_bytes + per_step) {
    size_t m = (ws_size - base_bytes) / per_step;
    Tc = (m >= T_STEPS) ? T_STEPS : (int)m;
  }

  zero_state<<<(2 * BATCH * HID + 255) / 256, 256, 0, stream>>>(v1, 2 * BATCH * HID);

  for (int t0 = 0; t0 < T_STEPS; t0 += Tc) {
    const int tc = (T_STEPS - t0 < Tc) ? (T_STEPS - t0) : Tc;
    dim3 grid(HID / BN, tc * BATCH / BM);
    gemm_fc1<<<grid, 256, 0, stream>>>(x + (size_t)t0 * BATCH * IN_F, w1, cur);
    lif_scan<<<(BATCH * HID) / 256, 256, 0, stream>>>(cur, v1, i1, tc);
    out_proj<<<BATCH, 256, 0, stream>>>(cur, wo,
                                        outcur + (size_t)t0 * BATCH * OUT_F, tc);
  }
  li_scan<<<(BATCH * OUT_F + 255) / 256, 256, 0, stream>>>(outcur, out);
}

// Round 2
// 1149.171 us; speedup vs baseline: 2.4737x; 2.4737x over previous
//
#include <hip/hip_runtime.h>
#include <cstdint>
#include <cstddef>

#define T_STEPS 64
#define BATCH 512
#define IN_F 784
#define HID 2048
#define OUT_F 10

#define DEC_V 0.9f   // 1 - dt*tau_mem_inv
#define DEC_I 0.8f   // 1 - dt*tau_syn_inv
#define DT_V 0.1f
#define V_TH 0.5f

typedef __attribute__((ext_vector_type(8))) short bf16x8;
typedef __attribute__((ext_vector_type(4))) float f32x4;
typedef __attribute__((ext_vector_type(4))) unsigned short us4;

// bf16 split helpers: hi = RTZ (cheap, 1 AND for float-back), lo = RTN of residual.
// Combined error ~2^-17 relative — fp32-class for this problem.
__device__ __forceinline__ unsigned short f2bf_rtn(float f) {
  unsigned int u = __float_as_uint(f);
  u += 0x7fffu + ((u >> 16) & 1u);
  return (unsigned short)(u >> 16);
}
__device__ __forceinline__ float bf_hi_f(float f) {
  return __uint_as_float(__float_as_uint(f) & 0xffff0000u);
}

// ---------------------------------------------------------------------------
// Precompute w1 split into bf16 hi/lo arrays (once per call; 6.4 MB in ws).
// ---------------------------------------------------------------------------
__global__ __launch_bounds__(256)
void split_w(const float* __restrict__ w, unsigned short* __restrict__ wh,
             unsigned short* __restrict__ wl, int n) {
  int i = blockIdx.x * 256 + threadIdx.x;
  if (i >= n) return;
  float v = w[i];
  float hf = bf_hi_f(v);
  wh[i] = (unsigned short)(__float_as_uint(v) >> 16);
  wl[i] = f2bf_rtn(v - hf);
}

// ---------------------------------------------------------------------------
// MFMA GEMM: C[m,n] = sum_k A[m,k] * W[n,k], fp32 via 4x bf16-split products.
// A fp32 [M,784]; W pre-split bf16 [2048,784] (hi/lo); C fp32 [M,2048].
// 128x128 block tile, 4 waves, each wave 64x64 = 4x4 tiles of 16x16x32.
// LDS k-stride 40 (pad 8): b128 frag reads are 2-way -> conflict-free.
// ---------------------------------------------------------------------------
#define BM 128
#define BN 128

__global__ __launch_bounds__(256, 2)
void gemm_fc1(const float* __restrict__ A, const unsigned short* __restrict__ WhG,
              const unsigned short* __restrict__ WlG, float* __restrict__ C) {
  __shared__ unsigned short Ah[128][40];
  __shared__ unsigned short Al[128][40];
  __shared__ unsigned short Wh[128][40];
  __shared__ unsigned short Wl[128][40];

  const int tid = threadIdx.x;
  const int bn = blockIdx.x * BN;
  const int bm = blockIdx.y * BM;

  // staging decomposition: each thread covers 4 rows x one 4-elem k-slice
  const int lm = tid >> 3;          // 0..31
  const int kk = (tid & 7) * 4;     // 0,4,...,28

  // compute decomposition
  const int lane = tid & 63;
  const int wv = tid >> 6;          // wave 0..3
  const int wr = (wv >> 1) * 64;
  const int wc = (wv & 1) * 64;
  const int col = lane & 15;
  const int quad = lane >> 4;

  f32x4 acc[4][4] = {};

  float4 av[4];
  us4 whv[4], wlv[4];
#pragma unroll
  for (int rep = 0; rep < 4; ++rep) {   // prefetch k-tile 0 (k<32 always valid)
    const int m = lm + rep * 32;
    av[rep]  = *(const float4*)&A[(size_t)(bm + m) * IN_F + kk];
    whv[rep] = *(const us4*)&WhG[(size_t)(bn + m) * IN_F + kk];
    wlv[rep] = *(const us4*)&WlG[(size_t)(bn + m) * IN_F + kk];
  }

  for (int k0 = 0; k0 < IN_F; k0 += 32) {
    __syncthreads();
#pragma unroll
    for (int rep = 0; rep < 4; ++rep) {
      const int m = lm + rep * 32;
      const float4 v = av[rep];
      us4 h4, l4;
      {
        float c0 = v.x, c1 = v.y, c2 = v.z, c3 = v.w;
        h4.x = (unsigned short)(__float_as_uint(c0) >> 16);
        h4.y = (unsigned short)(__float_as_uint(c1) >> 16);
        h4.z = (unsigned short)(__float_as_uint(c2) >> 16);
        h4.w = (unsigned short)(__float_as_uint(c3) >> 16);
        l4.x = f2bf_rtn(c0 - bf_hi_f(c0));
        l4.y = f2bf_rtn(c1 - bf_hi_f(c1));
        l4.z = f2bf_rtn(c2 - bf_hi_f(c2));
        l4.w = f2bf_rtn(c3 - bf_hi_f(c3));
      }
      *(us4*)&Ah[m][kk] = h4;
      *(us4*)&Al[m][kk] = l4;
      *(us4*)&Wh[m][kk] = whv[rep];
      *(us4*)&Wl[m][kk] = wlv[rep];
    }
    __syncthreads();

    const int kn = k0 + 32;
    if (kn < IN_F) {   // register prefetch of next k-tile overlaps MFMA
      const us4 zed = {0, 0, 0, 0};
#pragma unroll
      for (int rep = 0; rep < 4; ++rep) {
        const int m = lm + rep * 32;
        const int k = kn + kk;
        const bool ok = (k < IN_F);   // 784 = 24*32+16: zero-pad the tail tile
        av[rep]  = ok ? *(const float4*)&A[(size_t)(bm + m) * IN_F + k]
                      : make_float4(0.f, 0.f, 0.f, 0.f);
        whv[rep] = ok ? *(const us4*)&WhG[(size_t)(bn + m) * IN_F + k] : zed;
        wlv[rep] = ok ? *(const us4*)&WlG[(size_t)(bn + m) * IN_F + k] : zed;
      }
    }

    bf16x8 fah[4], fal[4], fwh[4], fwl[4];
#pragma unroll
    for (int i = 0; i < 4; ++i) {
      fah[i] = *(const bf16x8*)&Ah[wr + i * 16 + col][quad * 8];
      fal[i] = *(const bf16x8*)&Al[wr + i * 16 + col][quad * 8];
      fwh[i] = *(const bf16x8*)&Wh[wc + i * 16 + col][quad * 8];
      fwl[i] = *(const bf16x8*)&Wl[wc + i * 16 + col][quad * 8];
    }
#pragma unroll
    for (int mi = 0; mi < 4; ++mi)
#pragma unroll
      for (int ni = 0; ni < 4; ++ni) {
        acc[mi][ni] = __builtin_amdgcn_mfma_f32_16x16x32_bf16(fah[mi], fwh[ni], acc[mi][ni], 0, 0, 0);
        acc[mi][ni] = __builtin_amdgcn_mfma_f32_16x16x32_bf16(fah[mi], fwl[ni], acc[mi][ni], 0, 0, 0);
        acc[mi][ni] = __builtin_amdgcn_mfma_f32_16x16x32_bf16(fal[mi], fwh[ni], acc[mi][ni], 0, 0, 0);
        acc[mi][ni] = __builtin_amdgcn_mfma_f32_16x16x32_bf16(fal[mi], fwl[ni], acc[mi][ni], 0, 0, 0);
      }
  }

  // C/D layout (verified m89/m91): col = lane&15, row = (lane>>4)*4 + reg
#pragma unroll
  for (int mi = 0; mi < 4; ++mi)
#pragma unroll
    for (int ni = 0; ni < 4; ++ni)
#pragma unroll
      for (int r = 0; r < 4; ++r) {
        const int row = bm + wr + mi * 16 + quad * 4 + r;
        const int cg = bn + wc + ni * 16 + col;
        C[(size_t)row * HID + cg] = acc[mi][ni][r];
      }
}

// ---------------------------------------------------------------------------
// LIF state update over tc timesteps. One thread per (b,h). Overwrites cur
// with spike z in {0,1}. Order matches reference: v_dec uses OLD i.
// ---------------------------------------------------------------------------
__global__ __launch_bounds__(256)
void lif_scan(float* __restrict__ cur, float* __restrict__ v1,
              float* __restrict__ i1, int tc) {
  const int idx = blockIdx.x * 256 + threadIdx.x;  // b*HID + h
  float v = v1[idx];
  float ci = i1[idx];
  for (int t = 0; t < tc; ++t) {
    const size_t off = (size_t)t * (BATCH * HID) + idx;
    float c = cur[off];
    float vd = DEC_V * v + DT_V * ci;
    float z = (vd > V_TH) ? 1.0f : 0.0f;
    v = (1.0f - z) * vd;
    ci = DEC_I * ci + c;
    cur[off] = z;
  }
  v1[idx] = v;
  i1[idx] = ci;
}

// ---------------------------------------------------------------------------
// out_cur[row,o] = sum_h z[row,h]*wo[o,h]; row = t*B+b. One thread per row,
// dense FMA; wo index is wave-uniform -> scalar s_load + FMA w/ SGPR operand.
// ---------------------------------------------------------------------------
__global__ __launch_bounds__(128)
void out_proj(const float* __restrict__ z, const float* __restrict__ wo,
              float* __restrict__ outcur, int nrows) {
  const int row = blockIdx.x * 128 + threadIdx.x;
  if (row >= nrows) return;
  const float4* zr = (const float4*)(z + (size_t)row * HID);
  float acc[OUT_F] = {};
#pragma unroll 4
  for (int k4 = 0; k4 < HID / 4; ++k4) {
    const float4 zv = zr[k4];
#pragma unroll
    for (int o = 0; o < OUT_F; ++o) {
      const float* wop = wo + o * HID + k4 * 4;   // uniform address -> s_load
      acc[o] = fmaf(zv.x, wop[0], acc[o]);
      acc[o] = fmaf(zv.y, wop[1], acc[o]);
      acc[o] = fmaf(zv.z, wop[2], acc[o]);
      acc[o] = fmaf(zv.w, wop[3], acc[o]);
    }
  }
  float* op = outcur + (size_t)row * OUT_F;
#pragma unroll
  for (int o = 0; o < OUT_F; ++o) op[o] = acc[o];
}

// ---------------------------------------------------------------------------
// LI readout scan + max. One thread per (b,o). voltages[0]==0 so vmax=0 init.
// ---------------------------------------------------------------------------
__global__ __launch_bounds__(256)
void li_scan(const float* __restrict__ outcur, float* __restrict__ out) {
  const int idx = blockIdx.x * 256 + threadIdx.x;  // b*OUT_F + o
  if (idx >= BATCH * OUT_F) return;
  float vo = 0.f, io = 0.f, vmax = 0.f;
  for (int t = 0; t < T_STEPS; ++t) {
    float oc = outcur[(size_t)t * (BATCH * OUT_F) + idx];
    float von = DEC_V * vo + DT_V * io;
    io = DEC_I * io + oc;
    vo = von;
    vmax = fmaxf(vmax, von);
  }
  out[idx] = vmax;
}

__global__ void zero_state(float* __restrict__ p, int n) {
  int i = blockIdx.x * 256 + threadIdx.x;
  if (i < n) p[i] = 0.0f;
}

// ---------------------------------------------------------------------------
extern "C" void kernel_launch(void* const* d_in, const int* in_sizes, int n_in,
                              void* d_out, int out_size, void* d_ws, size_t ws_size,
                              hipStream_t stream) {
  const float* x  = (const float*)d_in[0];  // [T,B,1,28,28] -> [T*B, 784]
  const float* w1 = (const float*)d_in[1];  // [2048, 784]
  const float* wo = (const float*)d_in[2];  // [10, 2048]
  float* out = (float*)d_out;               // [512, 10]

  // ws layout: WhG | WlG (bf16 bits) | v1 | i1 | outcur | cur[Tc,B,HID]
  unsigned short* WhG = (unsigned short*)d_ws;
  unsigned short* WlG = WhG + (size_t)HID * IN_F;
  float* v1 = (float*)(WlG + (size_t)HID * IN_F);
  float* i1 = v1 + (size_t)BATCH * HID;
  float* outcur = i1 + (size_t)BATCH * HID;
  float* cur = outcur + (size_t)T_STEPS * BATCH * OUT_F;

  const size_t base_bytes =
      (size_t)2 * HID * IN_F * sizeof(unsigned short) +
      ((size_t)2 * BATCH * HID + (size_t)T_STEPS * BATCH * OUT_F) * sizeof(float);
  const size_t per_step = (size_t)BATCH * HID * sizeof(float);
  int Tc = 1;
  if (ws_size > base_bytes + per_step) {
    size_t m = (ws_size - base_bytes) / per_step;
    Tc = (m >= T_STEPS) ? T_STEPS : (int)m;
  }

  split_w<<<(HID * IN_F + 255) / 256, 256, 0, stream>>>(w1, WhG, WlG, HID * IN_F);
  zero_state<<<(2 * BATCH * HID + 255) / 256, 256, 0, stream>>>(v1, 2 * BATCH * HID);

  for (int t0 = 0; t0 < T_STEPS; t0 += Tc) {
    const int tc = (T_STEPS - t0 < Tc) ? (T_STEPS - t0) : Tc;
    dim3 grid(HID / BN, tc * BATCH / BM);
    gemm_fc1<<<grid, 256, 0, stream>>>(x + (size_t)t0 * BATCH * IN_F, WhG, WlG, cur);
    lif_scan<<<(BATCH * HID) / 256, 256, 0, stream>>>(cur, v1, i1, tc);
    const int nrows = tc * BATCH;
    out_proj<<<(nrows + 127) / 128, 128, 0, stream>>>(
        cur, wo, outcur + (size_t)t0 * BATCH * OUT_F, nrows);
  }
  li_scan<<<(BATCH * OUT_F + 255) / 256, 256, 0, stream>>>(outcur, out);
}

// Round 3
// 667.272 us; speedup vs baseline: 4.2602x; 1.7222x over previous
//
#include <hip/hip_runtime.h>
#include <cstdint>
#include <cstddef>

#define T_STEPS 64
#define BATCH 512
#define IN_F 784
#define KP 800          // IN_F padded to 25*32 so the K-loop has no tail
#define HID 2048
#define OUT_F 10

#define DEC_V 0.9f
#define DEC_I 0.8f
#define DT_V 0.1f
#define V_TH 0.5f

typedef __attribute__((ext_vector_type(8))) _Float16 f16x8;
typedef __attribute__((ext_vector_type(4))) float f32x4;

// DMA one 16B/lane chunk global->LDS (wave-uniform LDS base + lane*16).
__device__ __forceinline__ void load_lds16(const _Float16* g, _Float16* l) {
  __builtin_amdgcn_global_load_lds(
      (const __attribute__((address_space(1))) void*)g,
      (__attribute__((address_space(3))) void*)l, 16, 0, 0);
}

// ---------------------------------------------------------------------------
// Split fp32 rows into f16 hi/lo with K padded 784 -> 800 (pad = 0).
// a = hi + lo captures ~22 mantissa bits; dropped hi*lo cross term ~2^-24.
// ---------------------------------------------------------------------------
__global__ __launch_bounds__(256)
void split_rows(const float* __restrict__ src, _Float16* __restrict__ hi,
                _Float16* __restrict__ lo) {
  const int row = blockIdx.x;
  for (int k = threadIdx.x; k < KP; k += 256) {
    float v = (k < IN_F) ? src[(size_t)row * IN_F + k] : 0.0f;
    _Float16 h = (_Float16)v;               // RTN
    hi[(size_t)row * KP + k] = h;
    lo[(size_t)row * KP + k] = (_Float16)(v - (float)h);
  }
}

// wo fp32 [10,2048] -> f16 padded [16,2048] (rows 10..15 zero)
__global__ __launch_bounds__(256)
void pad_wo(const float* __restrict__ wo, _Float16* __restrict__ woF) {
  const int i = blockIdx.x * 256 + threadIdx.x;   // o*HID + h
  if (i >= 16 * HID) return;
  const int o = i / HID;
  woF[i] = (o < OUT_F) ? (_Float16)wo[i] : (_Float16)0.0f;
}

// ---------------------------------------------------------------------------
// MFMA GEMM: C[m,n] = sum_k A[m,k]*W[n,k], fp32 via 3x f16-split products.
// All operands pre-split f16 with row stride KP. 128x128 tile, 4 waves,
// each wave 4x4 of 16x16x32. Staging via global_load_lds width=16 into
// unpadded LDS [128][32] (frag reads are contiguous 1KB/wave: conflict-free).
// ---------------------------------------------------------------------------
__global__ __launch_bounds__(256, 2)
void gemm_fc1(const _Float16* __restrict__ Ah, const _Float16* __restrict__ Al,
              const _Float16* __restrict__ Wh, const _Float16* __restrict__ Wl,
              float* __restrict__ C) {
  __shared__ _Float16 sAh[128 * 32];
  __shared__ _Float16 sAl[128 * 32];
  __shared__ _Float16 sWh[128 * 32];
  __shared__ _Float16 sWl[128 * 32];

  const int tid = threadIdx.x;
  const int lane = tid & 63;
  const int wv = tid >> 6;
  const int bn = blockIdx.x * 128;
  const int bm = blockIdx.y * 128;

  // staging: wave wv covers rows wv*32..wv*32+31; per instr 16 rows x 32 halves
  const int sr = (lane >> 2);          // 0..15 row within instr
  const int skc = (lane & 3) * 8;      // k-halves offset 0/8/16/24

  // compute decomposition: wave -> 64x64 quadrant, 4x4 tiles of 16x16
  const int wr = (wv >> 1) * 64;
  const int wc = (wv & 1) * 64;
  const int col = lane & 15;
  const int quad = lane >> 4;

  f32x4 acc[4][4] = {};

  const size_t arow = (size_t)(bm + wv * 32 + sr) * KP + skc;
  const size_t wrow = (size_t)(bn + wv * 32 + sr) * KP + skc;
  _Float16* const ldsbase = (_Float16*)((wv * 32 + sr * 0) , (void*)0) ; // unused
  (void)ldsbase;

  for (int k0 = 0; k0 < KP; k0 += 32) {
    __syncthreads();   // previous tile's frag reads done before overwrite
#pragma unroll
    for (int j = 0; j < 2; ++j) {
      const int ro = wv * 32 + j * 16;             // wave-uniform
      load_lds16(Ah + arow + (size_t)j * 16 * KP + k0, sAh + ro * 32);
      load_lds16(Al + arow + (size_t)j * 16 * KP + k0, sAl + ro * 32);
      load_lds16(Wh + wrow + (size_t)j * 16 * KP + k0, sWh + ro * 32);
      load_lds16(Wl + wrow + (size_t)j * 16 * KP + k0, sWl + ro * 32);
    }
    __syncthreads();   // compiler emits s_waitcnt vmcnt(0) before barrier

    f16x8 fah[4], fal[4], fwh[4], fwl[4];
#pragma unroll
    for (int i = 0; i < 4; ++i) {
      fah[i] = *(const f16x8*)&sAh[(wr + i * 16 + col) * 32 + quad * 8];
      fal[i] = *(const f16x8*)&sAl[(wr + i * 16 + col) * 32 + quad * 8];
      fwh[i] = *(const f16x8*)&sWh[(wc + i * 16 + col) * 32 + quad * 8];
      fwl[i] = *(const f16x8*)&sWl[(wc + i * 16 + col) * 32 + quad * 8];
    }
#pragma unroll
    for (int mi = 0; mi < 4; ++mi)
#pragma unroll
      for (int ni = 0; ni < 4; ++ni) {
        acc[mi][ni] = __builtin_amdgcn_mfma_f32_16x16x32_f16(fah[mi], fwh[ni], acc[mi][ni], 0, 0, 0);
        acc[mi][ni] = __builtin_amdgcn_mfma_f32_16x16x32_f16(fah[mi], fwl[ni], acc[mi][ni], 0, 0, 0);
        acc[mi][ni] = __builtin_amdgcn_mfma_f32_16x16x32_f16(fal[mi], fwh[ni], acc[mi][ni], 0, 0, 0);
      }
  }

  // C/D layout: col = lane&15, row = (lane>>4)*4 + reg (verified in-situ R2)
#pragma unroll
  for (int mi = 0; mi < 4; ++mi)
#pragma unroll
    for (int ni = 0; ni < 4; ++ni)
#pragma unroll
      for (int r = 0; r < 4; ++r) {
        const int row = bm + wr + mi * 16 + quad * 4 + r;
        const int cg = bn + wc + ni * 16 + col;
        C[(size_t)row * HID + cg] = acc[mi][ni][r];
      }
}

// ---------------------------------------------------------------------------
// LIF update over tc steps. One thread per (b,h). Reads cur fp32, writes
// spikes z as f16 {0,1} (exact). Order matches reference (v_dec uses OLD i).
// ---------------------------------------------------------------------------
__global__ __launch_bounds__(256)
void lif_scan(const float* __restrict__ cur, _Float16* __restrict__ zF,
              float* __restrict__ v1, float* __restrict__ i1, int tc) {
  const int idx = blockIdx.x * 256 + threadIdx.x;  // b*HID + h
  float v = v1[idx];
  float ci = i1[idx];
  for (int t = 0; t < tc; ++t) {
    const size_t off = (size_t)t * (BATCH * HID) + idx;
    float c = cur[off];
    float vd = DEC_V * v + DT_V * ci;
    float z = (vd > V_TH) ? 1.0f : 0.0f;
    v = (1.0f - z) * vd;
    ci = DEC_I * ci + c;
    zF[off] = (_Float16)z;
  }
  v1[idx] = v;
  i1[idx] = ci;
}

// ---------------------------------------------------------------------------
// out_cur = z @ wo^T via MFMA: z f16 [nrows,2048] x woF f16 [16,2048].
// One wave per 16-row tile, K-loop 2048/32 = 64 MFMAs.
// ---------------------------------------------------------------------------
__global__ __launch_bounds__(256)
void out_proj(const _Float16* __restrict__ z, const _Float16* __restrict__ woF,
              float* __restrict__ outcur, int nrows) {
  const int wv = threadIdx.x >> 6;
  const int lane = threadIdx.x & 63;
  const int r0 = (blockIdx.x * 4 + wv) * 16;
  if (r0 >= nrows) return;
  const int col = lane & 15;
  const int quad = lane >> 4;
  const _Float16* zp = z + (size_t)(r0 + col) * HID + quad * 8;
  const _Float16* wp = woF + (size_t)col * HID + quad * 8;
  f32x4 acc = {};
#pragma unroll 8
  for (int k0 = 0; k0 < HID; k0 += 32) {
    f16x8 a = *(const f16x8*)(zp + k0);
    f16x8 b = *(const f16x8*)(wp + k0);
    acc = __builtin_amdgcn_mfma_f32_16x16x32_f16(a, b, acc, 0, 0, 0);
  }
  if (col < OUT_F) {
#pragma unroll
    for (int r = 0; r < 4; ++r)
      outcur[(size_t)(r0 + quad * 4 + r) * OUT_F + col] = acc[r];
  }
}

// ---------------------------------------------------------------------------
// LI readout scan + max. One thread per (b,o). voltages[0]==0 so vmax=0 init.
// ---------------------------------------------------------------------------
__global__ __launch_bounds__(256)
void li_scan(const float* __restrict__ outcur, float* __restrict__ out) {
  const int idx = blockIdx.x * 256 + threadIdx.x;  // b*OUT_F + o
  if (idx >= BATCH * OUT_F) return;
  float vo = 0.f, io = 0.f, vmax = 0.f;
  for (int t = 0; t < T_STEPS; ++t) {
    float oc = outcur[(size_t)t * (BATCH * OUT_F) + idx];
    float von = DEC_V * vo + DT_V * io;
    io = DEC_I * io + oc;
    vo = von;
    vmax = fmaxf(vmax, von);
  }
  out[idx] = vmax;
}

__global__ void zero_state(float* __restrict__ p, int n) {
  int i = blockIdx.x * 256 + threadIdx.x;
  if (i < n) p[i] = 0.0f;
}

// ---------------------------------------------------------------------------
extern "C" void kernel_launch(void* const* d_in, const int* in_sizes, int n_in,
                              void* d_out, int out_size, void* d_ws, size_t ws_size,
                              hipStream_t stream) {
  const float* x  = (const float*)d_in[0];  // [T*B, 784]
  const float* w1 = (const float*)d_in[1];  // [2048, 784]
  const float* wo = (const float*)d_in[2];  // [10, 2048]
  float* out = (float*)d_out;               // [512, 10]

  const size_t BH = (size_t)BATCH * HID;

  // fixed region: v1 | i1 | outcur | WhG | WlG | woF
  float* v1 = (float*)d_ws;
  float* i1 = v1 + BH;
  float* outcur = i1 + BH;
  _Float16* WhG = (_Float16*)(outcur + (size_t)T_STEPS * BATCH * OUT_F);
  _Float16* WlG = WhG + (size_t)HID * KP;
  _Float16* woF = WlG + (size_t)HID * KP;
  char* chunk0 = (char*)(woF + 16 * HID);

  const size_t base_bytes = (size_t)(chunk0 - (char*)d_ws);
  // per step: cur f32 [B,HID] + Ah/Al f16 [B,KP] + z f16 [B,HID]
  const size_t per_step = BH * 4 + (size_t)2 * BATCH * KP * 2 + BH * 2;
  int Tc = 1;
  if (ws_size > base_bytes + per_step) {
    size_t m = (ws_size - base_bytes) / per_step;
    Tc = (m >= T_STEPS) ? T_STEPS : (int)m;
  }

  // chunk region: cur | AhC | AlC | zF
  float* cur = (float*)chunk0;
  _Float16* AhC = (_Float16*)(cur + (size_t)Tc * BH);
  _Float16* AlC = AhC + (size_t)Tc * BATCH * KP;
  _Float16* zF  = AlC + (size_t)Tc * BATCH * KP;

  split_rows<<<HID, 256, 0, stream>>>(w1, WhG, WlG);
  pad_wo<<<(16 * HID + 255) / 256, 256, 0, stream>>>(wo, woF);
  zero_state<<<(int)((2 * BH + 255) / 256), 256, 0, stream>>>(v1, (int)(2 * BH));

  for (int t0 = 0; t0 < T_STEPS; t0 += Tc) {
    const int tc = (T_STEPS - t0 < Tc) ? (T_STEPS - t0) : Tc;
    const int nrows = tc * BATCH;
    split_rows<<<nrows, 256, 0, stream>>>(x + (size_t)t0 * BATCH * IN_F, AhC, AlC);
    dim3 grid(HID / 128, nrows / 128);
    gemm_fc1<<<grid, 256, 0, stream>>>(AhC, AlC, WhG, WlG, cur);
    lif_scan<<<(int)(BH / 256), 256, 0, stream>>>(cur, zF, v1, i1, tc);
    out_proj<<<(nrows + 63) / 64, 256, 0, stream>>>(
        zF, woF, outcur + (size_t)t0 * BATCH * OUT_F, nrows);
  }
  li_scan<<<(BATCH * OUT_F + 255) / 256, 256, 0, stream>>>(outcur, out);
}

// Round 4
// 639.465 us; speedup vs baseline: 4.4454x; 1.0435x over previous
//
#include <hip/hip_runtime.h>
#include <cstdint>
#include <cstddef>

#define T_STEPS 64
#define BATCH 512
#define IN_F 784
#define KP 800          // IN_F padded to 25*32: no K tail in gemm
#define HID 2048
#define OUT_F 10

#define DEC_V 0.9f
#define DEC_I 0.8f
#define DT_V 0.1f
#define V_TH 0.5f

typedef __attribute__((ext_vector_type(8))) _Float16 f16x8;
typedef __attribute__((ext_vector_type(4))) _Float16 f16x4;
typedef __attribute__((ext_vector_type(4))) float f32x4;

// DMA 16B/lane global->LDS (wave-uniform LDS base + lane*16).
__device__ __forceinline__ void load_lds16(const _Float16* g, _Float16* l) {
  __builtin_amdgcn_global_load_lds(
      (const __attribute__((address_space(1))) void*)g,
      (__attribute__((address_space(3))) void*)l, 16, 0, 0);
}

// ---------------------------------------------------------------------------
// Split fp32 rows into f16 hi/lo, K padded 784 -> 800 (pad zeros).
// a = hi + lo keeps ~22 mantissa bits; dropped lo*lo cross term ~2^-24.
// 2 rows per block, float4 loads, f16x4 stores.
// ---------------------------------------------------------------------------
__global__ __launch_bounds__(256)
void split_rows(const float* __restrict__ src, _Float16* __restrict__ hi,
                _Float16* __restrict__ lo) {
  const int row = blockIdx.x * 2 + (threadIdx.x >> 7);
  const int ln = threadIdx.x & 127;
  const float4* s = (const float4*)(src + (size_t)row * IN_F);
#pragma unroll
  for (int it = 0; it < 2; ++it) {
    const int q = ln + it * 128;               // quad index, 200 per row
    if (q >= 200) break;
    float4 v = (q < 196) ? s[q] : make_float4(0.f, 0.f, 0.f, 0.f);
    f16x4 h, l;
    h.x = (_Float16)v.x; l.x = (_Float16)(v.x - (float)h.x);
    h.y = (_Float16)v.y; l.y = (_Float16)(v.y - (float)h.y);
    h.z = (_Float16)v.z; l.z = (_Float16)(v.z - (float)h.z);
    h.w = (_Float16)v.w; l.w = (_Float16)(v.w - (float)h.w);
    *(f16x4*)&hi[(size_t)row * KP + q * 4] = h;
    *(f16x4*)&lo[(size_t)row * KP + q * 4] = l;
  }
}

// ---------------------------------------------------------------------------
// MFMA GEMM: C[m,n] = sum_k A[m,k]*W[n,k], fp32 via 3x f16-split products.
// 128x128 tile, 4 waves x (4x4 of 16x16x32). global_load_lds width=16.
// ---------------------------------------------------------------------------
__global__ __launch_bounds__(256, 4)
void gemm_fc1(const _Float16* __restrict__ Ah, const _Float16* __restrict__ Al,
              const _Float16* __restrict__ Wh, const _Float16* __restrict__ Wl,
              float* __restrict__ C) {
  __shared__ _Float16 sAh[128 * 32];
  __shared__ _Float16 sAl[128 * 32];
  __shared__ _Float16 sWh[128 * 32];
  __shared__ _Float16 sWl[128 * 32];

  const int tid = threadIdx.x;
  const int lane = tid & 63;
  const int wv = tid >> 6;
  const int bn = blockIdx.x * 128;
  const int bm = blockIdx.y * 128;

  const int sr = lane >> 2;            // staging row within 16-row group
  const int skc = (lane & 3) * 8;      // k offset 0/8/16/24 halves

  const int wr = (wv >> 1) * 64;
  const int wc = (wv & 1) * 64;
  const int col = lane & 15;
  const int quad = lane >> 4;

  f32x4 acc[4][4] = {};

  const size_t arow = (size_t)(bm + wv * 32 + sr) * KP + skc;
  const size_t wrow = (size_t)(bn + wv * 32 + sr) * KP + skc;

  for (int k0 = 0; k0 < KP; k0 += 32) {
    __syncthreads();
#pragma unroll
    for (int j = 0; j < 2; ++j) {
      const int ro = wv * 32 + j * 16;
      load_lds16(Ah + arow + (size_t)j * 16 * KP + k0, sAh + ro * 32);
      load_lds16(Al + arow + (size_t)j * 16 * KP + k0, sAl + ro * 32);
      load_lds16(Wh + wrow + (size_t)j * 16 * KP + k0, sWh + ro * 32);
      load_lds16(Wl + wrow + (size_t)j * 16 * KP + k0, sWl + ro * 32);
    }
    __syncthreads();

    f16x8 fah[4], fal[4], fwh[4], fwl[4];
#pragma unroll
    for (int i = 0; i < 4; ++i) {
      fah[i] = *(const f16x8*)&sAh[(wr + i * 16 + col) * 32 + quad * 8];
      fal[i] = *(const f16x8*)&sAl[(wr + i * 16 + col) * 32 + quad * 8];
      fwh[i] = *(const f16x8*)&sWh[(wc + i * 16 + col) * 32 + quad * 8];
      fwl[i] = *(const f16x8*)&sWl[(wc + i * 16 + col) * 32 + quad * 8];
    }
#pragma unroll
    for (int mi = 0; mi < 4; ++mi)
#pragma unroll
      for (int ni = 0; ni < 4; ++ni) {
        acc[mi][ni] = __builtin_amdgcn_mfma_f32_16x16x32_f16(fah[mi], fwh[ni], acc[mi][ni], 0, 0, 0);
        acc[mi][ni] = __builtin_amdgcn_mfma_f32_16x16x32_f16(fah[mi], fwl[ni], acc[mi][ni], 0, 0, 0);
        acc[mi][ni] = __builtin_amdgcn_mfma_f32_16x16x32_f16(fal[mi], fwh[ni], acc[mi][ni], 0, 0, 0);
      }
  }

  // C/D layout: col = lane&15, row = quad*4 + reg
#pragma unroll
  for (int mi = 0; mi < 4; ++mi)
#pragma unroll
    for (int ni = 0; ni < 4; ++ni)
#pragma unroll
      for (int r = 0; r < 4; ++r) {
        const int row = bm + wr + mi * 16 + quad * 4 + r;
        const int cg = bn + wc + ni * 16 + col;
        C[(size_t)row * HID + cg] = acc[mi][ni][r];
      }
}

// ---------------------------------------------------------------------------
// Fused LIF scan + output projection partials.
// Block = (hc = blockIdx.x in [0,8), b = blockIdx.y). Phase 1: serial LIF
// over tc steps for 256 h, spikes -> LDS z[t][h] f16. Phase 2: 8 MFMAs per
// wave compute z(64t x 256h) @ woT(256h x 16o); store partials per chunk.
// outP[hc][t_global][b][o] — every (hc,t,b,o<10) written once across chunks.
// ---------------------------------------------------------------------------
__global__ __launch_bounds__(256)
void lif_out(const float* __restrict__ cur, const float* __restrict__ wo,
             float* __restrict__ v1, float* __restrict__ i1,
             float* __restrict__ outP, int tc, int t0) {
  __shared__ _Float16 zL[T_STEPS][264];   // stride 264 halves: 16B-aligned rows
  __shared__ _Float16 wT[16][264];

  const int tid = threadIdx.x;
  const int hc = blockIdx.x;
  const int b = blockIdx.y;
  const int hb = hc * 256;

  // load w_out chunk -> LDS (rows 10..15 zero)
  for (int i = tid; i < 16 * 256; i += 256) {
    const int n = i >> 8, k = i & 255;
    wT[n][k] = (n < OUT_F) ? (_Float16)wo[(size_t)n * HID + hb + k] : (_Float16)0.f;
  }

  // phase 1: LIF serial scan, one thread per h
  const int sidx = b * HID + hb + tid;
  float v = v1[sidx];
  float ci = i1[sidx];
#pragma unroll 4
  for (int t = 0; t < tc; ++t) {
    const float c = cur[(size_t)t * (BATCH * HID) + sidx];
    const float vd = DEC_V * v + DT_V * ci;
    const float z = (vd > V_TH) ? 1.0f : 0.0f;
    v = (1.0f - z) * vd;
    ci = DEC_I * ci + c;
    zL[t][tid] = (_Float16)z;
  }
  v1[sidx] = v;
  i1[sidx] = ci;
  __syncthreads();

  // phase 2: wave wv handles t-tile [wv*16, wv*16+16)
  const int wv = tid >> 6;
  const int lane = tid & 63;
  const int col = lane & 15;
  const int quad = lane >> 4;
  f32x4 acc = {};
  const _Float16* za = &zL[wv * 16 + col][0];
  const _Float16* wb = &wT[col][0];
#pragma unroll
  for (int ks = 0; ks < 8; ++ks) {
    f16x8 a = *(const f16x8*)(za + ks * 32 + quad * 8);
    f16x8 bb = *(const f16x8*)(wb + ks * 32 + quad * 8);
    acc = __builtin_amdgcn_mfma_f32_16x16x32_f16(a, bb, acc, 0, 0, 0);
  }
  if (col < OUT_F) {
#pragma unroll
    for (int r = 0; r < 4; ++r) {
      const int t = wv * 16 + quad * 4 + r;
      if (t < tc)
        outP[(((size_t)hc * T_STEPS + (t0 + t)) * BATCH + b) * OUT_F + col] = acc[r];
    }
  }
}

// ---------------------------------------------------------------------------
// LI readout: sum 8 chunk partials, scan, max. One thread per (b,o).
// ---------------------------------------------------------------------------
__global__ __launch_bounds__(256)
void li_scan(const float* __restrict__ outP, float* __restrict__ out) {
  const int idx = blockIdx.x * 256 + threadIdx.x;  // b*OUT_F + o
  if (idx >= BATCH * OUT_F) return;
  float vo = 0.f, io = 0.f, vmax = 0.f;
  for (int t = 0; t < T_STEPS; ++t) {
    float oc = 0.f;
#pragma unroll
    for (int hc = 0; hc < 8; ++hc)
      oc += outP[((size_t)hc * T_STEPS + t) * (BATCH * OUT_F) + idx];
    const float von = DEC_V * vo + DT_V * io;
    io = DEC_I * io + oc;
    vo = von;
    vmax = fmaxf(vmax, von);
  }
  out[idx] = vmax;
}

__global__ void zero_state(float* __restrict__ p, int n) {
  int i = blockIdx.x * 256 + threadIdx.x;
  if (i < n) p[i] = 0.0f;
}

// ---------------------------------------------------------------------------
extern "C" void kernel_launch(void* const* d_in, const int* in_sizes, int n_in,
                              void* d_out, int out_size, void* d_ws, size_t ws_size,
                              hipStream_t stream) {
  const float* x  = (const float*)d_in[0];  // [T*B, 784]
  const float* w1 = (const float*)d_in[1];  // [2048, 784]
  const float* wo = (const float*)d_in[2];  // [10, 2048]
  float* out = (float*)d_out;               // [512, 10]

  const size_t BH = (size_t)BATCH * HID;

  // fixed region: v1 | i1 | outP[8][T*B*10] | WhG | WlG
  float* v1 = (float*)d_ws;
  float* i1 = v1 + BH;
  float* outP = i1 + BH;
  _Float16* WhG = (_Float16*)(outP + (size_t)8 * T_STEPS * BATCH * OUT_F);
  _Float16* WlG = WhG + (size_t)HID * KP;
  char* chunk0 = (char*)(WlG + (size_t)HID * KP);

  const size_t base_bytes = (size_t)(chunk0 - (char*)d_ws);
  // per step: cur f32 [B,HID] + Ah/Al f16 [B,KP]
  const size_t per_step = BH * 4 + (size_t)2 * BATCH * KP * 2;
  int Tc = 1;
  if (ws_size > base_bytes + per_step) {
    size_t m = (ws_size - base_bytes) / per_step;
    Tc = (m >= T_STEPS) ? T_STEPS : (int)m;
  }

  float* cur = (float*)chunk0;
  _Float16* AhC = (_Float16*)(cur + (size_t)Tc * BH);
  _Float16* AlC = AhC + (size_t)Tc * BATCH * KP;

  split_rows<<<HID / 2, 256, 0, stream>>>(w1, WhG, WlG);
  zero_state<<<(int)((2 * BH + 255) / 256), 256, 0, stream>>>(v1, (int)(2 * BH));

  for (int t0 = 0; t0 < T_STEPS; t0 += Tc) {
    const int tc = (T_STEPS - t0 < Tc) ? (T_STEPS - t0) : Tc;
    const int nrows = tc * BATCH;
    split_rows<<<nrows / 2, 256, 0, stream>>>(x + (size_t)t0 * BATCH * IN_F, AhC, AlC);
    dim3 grid(HID / 128, nrows / 128);
    gemm_fc1<<<grid, 256, 0, stream>>>(AhC, AlC, WhG, WlG, cur);
    dim3 lgrid(HID / 256, BATCH);
    lif_out<<<lgrid, 256, 0, stream>>>(cur, wo, v1, i1, outP, tc, t0);
  }
  li_scan<<<(BATCH * OUT_F + 255) / 256, 256, 0, stream>>>(outP, out);
}